// Round 17
// baseline (407.681 us; speedup 1.0000x reference)
//
#include <hip/hip_runtime.h>
#include <hip/hip_bf16.h>

#define NNODES 20000
#define NEDGES 320000
#define NGRAPH 1000

typedef __hip_bfloat16 bf16;
typedef unsigned short u16;
typedef short short8 __attribute__((ext_vector_type(8)));
typedef float f32x4 __attribute__((ext_vector_type(4)));
typedef float f32x2 __attribute__((ext_vector_type(2)));

__device__ __forceinline__ float b2f(bf16 x) { return __bfloat162float(x); }
__device__ __forceinline__ float bu2f(u16 u) { return __uint_as_float(((unsigned)u) << 16); }
__device__ __forceinline__ float lou(unsigned u) { return __uint_as_float(u << 16); }
__device__ __forceinline__ float hiu(unsigned u) { return __uint_as_float(u & 0xffff0000u); }
__device__ __forceinline__ u16 f2bu(float v) {
    __hip_bfloat16 b = __float2bfloat16(v);  // RNE
    return *reinterpret_cast<u16*>(&b);
}

// packed-fp32 helpers: map to v_pk_fma_f32 / v_pk_max_f32 etc. (VOP3P)
__device__ __forceinline__ f32x2 pk2(float a, float b) { f32x2 r; r.x = a; r.y = b; return r; }
__device__ __forceinline__ f32x2 psplat(float a) { f32x2 r; r.x = a; r.y = a; return r; }
__device__ __forceinline__ f32x2 pfma(f32x2 a, f32x2 b, f32x2 c) {
    return __builtin_elementwise_fma(a, b, c);
}
__device__ __forceinline__ f32x2 pmax(f32x2 a, f32x2 b) {
    return __builtin_elementwise_max(a, b);
}

// width-agnostic index fetch (int32 or int64 storage)
__device__ __forceinline__ int idx_at(const void* p, int i, int is64) {
    return is64 ? (int)((const long long*)p)[i] : ((const int*)p)[i];
}

// raw float input fetch (bf16 or fp32 storage)
__device__ __forceinline__ float raw_at(const void* p, size_t i, bool isbf) {
    return isbf ? b2f(((const bf16*)p)[i]) : ((const float*)p)[i];
}

static inline char* align16(char* p) {
    return (char*)(((uintptr_t)p + 15) & ~(uintptr_t)15);
}

// ---------------------------------------------------------------------------
// sniff input encodings (flags[0]: floats bf16?, flags[1]: ei int64?, flags[2]: batch int64?)
// ---------------------------------------------------------------------------
__global__ void sniff_all(const void* __restrict__ x, const void* __restrict__ ei,
                          const void* __restrict__ batch, int* __restrict__ flags) {
    __shared__ int sb[4];
    if (threadIdx.x < 4) sb[threadIdx.x] = 0;
    __syncthreads();
    int gb = 0, gf = 0, ze = 0, zb = 0;
    for (int i = threadIdx.x; i < 8192; i += blockDim.x) {
        float vb = b2f(((const bf16*)x)[i]);
        float vf = ((const float*)x)[i];
        if (fabsf(vb) < 1e4f) gb++;
        if (fabsf(vf) < 1e4f) gf++;
        if (((const int*)ei)[2 * i + 1] == 0) ze++;
        if (((const int*)batch)[2 * i + 1] == 0) zb++;
    }
    atomicAdd(&sb[0], gb); atomicAdd(&sb[1], gf);
    atomicAdd(&sb[2], ze); atomicAdd(&sb[3], zb);
    __syncthreads();
    if (threadIdx.x == 0) {
        flags[0] = (sb[0] >= sb[1]) ? 1 : 0;
        flags[1] = (sb[2] > 6000) ? 1 : 0;
        flags[2] = (sb[3] > 6000) ? 1 : 0;
    }
}

// ---------------------------------------------------------------------------
// fused preprocessing: convert-to-fp32 | ea->bf16 | 4x W fragment-pack |
// DEG zero | POOL/CNT zero. All source reads from RAW inputs.
// ---------------------------------------------------------------------------
struct Segs {
    const void* src[29];
    int off[30];
};

__device__ __forceinline__ void wtp_store(u16* __restrict__ dst, const void* __restrict__ src,
                                          int K, int N, int i, bool isbf) {
    int j = i & 7;
    int lane = (i >> 3) & 63;
    int rest = i >> 9;
    int KB = K >> 5;
    int tile = rest / KB, kbi = rest - tile * KB;
    int l16 = lane & 15, quad = lane >> 4;
    int n = tile * 16 + l16;
    int kk = kbi * 32 + quad * 8 + j;
    dst[i] = f2bu(raw_at(src, (size_t)kk * N + n, isbf));
}

__global__ void preprocess(Segs S, const int* __restrict__ flags,
                           float* __restrict__ conv, int total,
                           u16* __restrict__ eah,
                           u16* __restrict__ wt2l, u16* __restrict__ wt2r,
                           u16* __restrict__ wt3l, u16* __restrict__ wt3r,
                           int* __restrict__ deg, float* __restrict__ poolcnt) {
    int i = blockIdx.x * blockDim.x + threadIdx.x;
    bool isbf = flags[0] != 0;
    if (i < total) {
        int lo = 0, hi = 29;
        while (hi - lo > 1) {
            int mid = (lo + hi) >> 1;
            if (i >= S.off[mid]) lo = mid; else hi = mid;
        }
        conv[i] = raw_at(S.src[lo], i - S.off[lo], isbf);
        return;
    }
    i -= total;
    if (i < NEDGES * 4) {                       // edge_attr -> bf16 (raw read)
        eah[i] = isbf ? ((const u16*)S.src[1])[i] : f2bu(((const float*)S.src[1])[i]);
        return;
    }
    i -= NEDGES * 4;
    if (i < 65536) { wtp_store(wt2l, S.src[9],  256, 256, i, isbf); return; }
    i -= 65536;
    if (i < 65536) { wtp_store(wt2r, S.src[11], 256, 256, i, isbf); return; }
    i -= 65536;
    if (i < 16384) { wtp_store(wt3l, S.src[16], 256, 64, i, isbf); return; }
    i -= 16384;
    if (i < 16384) { wtp_store(wt3r, S.src[18], 256, 64, i, isbf); return; }
    i -= 16384;
    if (i < NNODES) { deg[i] = 0; return; }
    i -= NNODES;
    if (i < NGRAPH * 65) poolcnt[i] = 0.f;
}

// ---------------------------------------------------------------------------
// CSR build: histogram -> shfl-scan -> scatter (dst-sorted edge list)
// ---------------------------------------------------------------------------
__global__ void csr_hist(const void* __restrict__ ei, const int* __restrict__ flags,
                         int* __restrict__ deg) {
    int e = blockIdx.x * blockDim.x + threadIdx.x;
    if (e >= NEDGES) return;
    atomicAdd(&deg[idx_at(ei, NEDGES + e, flags[1])], 1);
}

__global__ void csr_scan(const int* __restrict__ deg, int* __restrict__ rowptr,
                         int* __restrict__ cursor) {
    __shared__ int wsum[16];
    __shared__ int wpre[16];
    const int t = threadIdx.x;
    const int wid = t >> 6, lane = t & 63;
    const int base = t * 20;
    int loc[20];
    int s = 0;
#pragma unroll
    for (int j = 0; j < 20; j++) {
        int i = base + j;
        int v = (i < NNODES) ? deg[i] : 0;
        loc[j] = s;
        s += v;
    }
    int incl = s;
#pragma unroll
    for (int o = 1; o < 64; o <<= 1) {
        int n = __shfl_up(incl, o);
        if (lane >= o) incl += n;
    }
    if (lane == 63) wsum[wid] = incl;
    __syncthreads();
    if (wid == 0 && lane < 16) {
        int v = wsum[lane];
        int inc2 = v;
#pragma unroll
        for (int o = 1; o < 16; o <<= 1) {
            int n = __shfl_up(inc2, o);
            if (lane >= o) inc2 += n;
        }
        wpre[lane] = inc2 - v;
    }
    __syncthreads();
    int excl = wpre[wid] + incl - s;
#pragma unroll
    for (int j = 0; j < 20; j++) {
        int i = base + j;
        if (i < NNODES) { rowptr[i] = excl + loc[j]; cursor[i] = excl + loc[j]; }
    }
    if (t == 1023) rowptr[NNODES] = excl + s;
}

__global__ void csr_scatter(const void* __restrict__ ei, const int* __restrict__ flags,
                            int* __restrict__ cursor, int2* __restrict__ csr) {
    int e = blockIdx.x * blockDim.x + threadIdx.x;
    if (e >= NEDGES) return;
    const int i64 = flags[1];
    int src = idx_at(ei, e, i64), dst = idx_at(ei, NEDGES + e, i64);
    int pos = atomicAdd(&cursor[dst], 1);
    csr[pos] = make_int2(src, e);
}

// ---------------------------------------------------------------------------
// VALU GEMM (layer 1, CIN=12): XL = X@Wl+bl (bf16), XR = X@Wr+br (fp32)
// ---------------------------------------------------------------------------
template <int TM, int CIN, int DOUT, bool GUARD>
__global__ __launch_bounds__(256, 2) void lin_gemm(
        const float* __restrict__ X,
        const float* __restrict__ Wl, const float* __restrict__ bl,
        const float* __restrict__ Wr, const float* __restrict__ br,
        u16* __restrict__ XL, float* __restrict__ XR) {
    constexpr int CPT = DOUT / 4;
    constexpr int RG = 256 / CPT;
    constexpr int M = RG * TM;
    __shared__ float xs[M * CIN];

    const int t = threadIdx.x;
    const int ct = t % CPT;
    const int rg = t / CPT;
    const int c0 = ct * 4;
    const int r0 = blockIdx.x * M;

    constexpr int C4 = CIN / 4;
    for (int i = t; i < M * C4; i += 256) {
        int r = i / C4, j = i - r * C4;
        float4 v = make_float4(0.f, 0.f, 0.f, 0.f);
        if (!GUARD || (r0 + r) < NNODES)
            v = *(const float4*)&X[(size_t)(r0 + r) * CIN + j * 4];
        *(float4*)&xs[r * CIN + j * 4] = v;
    }
    __syncthreads();

    float4 accL[TM], accR[TM];
#pragma unroll
    for (int m = 0; m < TM; m++) {
        accL[m] = make_float4(0.f, 0.f, 0.f, 0.f);
        accR[m] = make_float4(0.f, 0.f, 0.f, 0.f);
    }
    const float* xbase = &xs[rg * TM * CIN];
#pragma unroll 4
    for (int k = 0; k < CIN; k++) {
        const float4 wl = *(const float4*)&Wl[k * DOUT + c0];
        const float4 wr = *(const float4*)&Wr[k * DOUT + c0];
#pragma unroll
        for (int m = 0; m < TM; m++) {
            float xv = xbase[m * CIN + k];
            accL[m].x = fmaf(xv, wl.x, accL[m].x);
            accL[m].y = fmaf(xv, wl.y, accL[m].y);
            accL[m].z = fmaf(xv, wl.z, accL[m].z);
            accL[m].w = fmaf(xv, wl.w, accL[m].w);
            accR[m].x = fmaf(xv, wr.x, accR[m].x);
            accR[m].y = fmaf(xv, wr.y, accR[m].y);
            accR[m].z = fmaf(xv, wr.z, accR[m].z);
            accR[m].w = fmaf(xv, wr.w, accR[m].w);
        }
    }

    const float4 b4l = *(const float4*)&bl[c0];
    const float4 b4r = *(const float4*)&br[c0];
#pragma unroll
    for (int m = 0; m < TM; m++) {
        int row = r0 + rg * TM + m;
        if (GUARD && row >= NNODES) continue;
        float l0 = accL[m].x + b4l.x, l1 = accL[m].y + b4l.y;
        float l2 = accL[m].z + b4l.z, l3 = accL[m].w + b4l.w;
        uint2 pk;
        pk.x = (unsigned)f2bu(l0) | ((unsigned)f2bu(l1) << 16);
        pk.y = (unsigned)f2bu(l2) | ((unsigned)f2bu(l3) << 16);
        *(uint2*)&XL[(size_t)row * DOUT + c0] = pk;
        float4 r4;
        r4.x = accR[m].x + b4r.x; r4.y = accR[m].y + b4r.y;
        r4.z = accR[m].z + b4r.z; r4.w = accR[m].w + b4r.w;
        *(float4*)&XR[(size_t)row * DOUT + c0] = r4;
    }
}

// ---------------------------------------------------------------------------
// MFMA GEMM (layers 2/3): XL = X@Wl+bl (bf16 out), XR = X@Wr+br (fp32 out).
// ---------------------------------------------------------------------------
template <int N>
__global__ __launch_bounds__(256) void lin_gemm_mfma(
        const float* __restrict__ X,
        const u16* __restrict__ WlP, const float* __restrict__ bl,
        const u16* __restrict__ WrP, const float* __restrict__ br,
        u16* __restrict__ XL, float* __restrict__ XR) {
    constexpr int K = 256;
    constexpr int KB = K / 32;
    constexpr int NTW = N / 64;
    constexpr int XSTR = 264;
    __shared__ u16 xhi[16 * XSTR];
    __shared__ u16 xlo[16 * XSTR];

    const int t = threadIdx.x;
    const int w = t >> 6, lane = t & 63;
    const int quad = lane >> 4, l16 = lane & 15;
    const int m0 = blockIdx.x * 16;
    const int nbase = w * (N / 4);

    for (int idx = t; idx < 16 * 64; idx += 256) {
        int r = idx >> 6, c4 = idx & 63;
        float4 v = *(const float4*)&X[(size_t)(m0 + r) * K + c4 * 4];
        float f[4] = {v.x, v.y, v.z, v.w};
        ushort4 hi, lo;
        u16 h;
        h = f2bu(f[0]); hi.x = h; lo.x = f2bu(f[0] - bu2f(h));
        h = f2bu(f[1]); hi.y = h; lo.y = f2bu(f[1] - bu2f(h));
        h = f2bu(f[2]); hi.z = h; lo.z = f2bu(f[2] - bu2f(h));
        h = f2bu(f[3]); hi.w = h; lo.w = f2bu(f[3] - bu2f(h));
        *(ushort4*)&xhi[r * XSTR + c4 * 4] = hi;
        *(ushort4*)&xlo[r * XSTR + c4 * 4] = lo;
    }
    __syncthreads();

    f32x4 accL[NTW], accR[NTW];
#pragma unroll
    for (int i = 0; i < NTW; i++) {
        accL[i] = (f32x4){0.f, 0.f, 0.f, 0.f};
        accR[i] = (f32x4){0.f, 0.f, 0.f, 0.f};
    }

    const int abase = l16 * XSTR + quad * 8;
#pragma unroll
    for (int kbi = 0; kbi < KB; kbi++) {
        short8 ahi = *(const short8*)&xhi[abase + kbi * 32];
        short8 alo = *(const short8*)&xlo[abase + kbi * 32];
#pragma unroll
        for (int i = 0; i < NTW; i++) {
            int tg = (nbase >> 4) + i;
            size_t off = ((size_t)(tg * KB + kbi) * 64 + lane) * 8;
            short8 bL = *(const short8*)&WlP[off];
            short8 bR = *(const short8*)&WrP[off];
            accL[i] = __builtin_amdgcn_mfma_f32_16x16x32_bf16(ahi, bL, accL[i], 0, 0, 0);
            accL[i] = __builtin_amdgcn_mfma_f32_16x16x32_bf16(alo, bL, accL[i], 0, 0, 0);
            accR[i] = __builtin_amdgcn_mfma_f32_16x16x32_bf16(ahi, bR, accR[i], 0, 0, 0);
            accR[i] = __builtin_amdgcn_mfma_f32_16x16x32_bf16(alo, bR, accR[i], 0, 0, 0);
        }
    }

#pragma unroll
    for (int i = 0; i < NTW; i++) {
        int col = nbase + i * 16 + l16;
        float bLv = bl[col], bRv = br[col];
#pragma unroll
        for (int r = 0; r < 4; r++) {
            int row = m0 + quad * 4 + r;
            XL[(size_t)row * N + col] = f2bu(accL[i][r] + bLv);
            XR[(size_t)row * N + col] = accR[i][r] + bRv;
        }
    }
}

// ---------------------------------------------------------------------------
// Fused GATv2 edge pipeline (round-16 structure: one block per dst, one wave
// per head, 4 groups x 16 lanes, lane owns 4 channels). Channel math packed
// into float2 -> v_pk_fma_f32 / v_pk_max_f32 (VOP3P, 2 fp32 ops/inst): same
// geometry/registers, ~30% fewer VALU instructions per edge.
// POOLF: fuse global mean-pool atomics into the epilogue (layer 3).
// ---------------------------------------------------------------------------
template <int H, bool ELU, bool POOLF>
__global__ __launch_bounds__(H * 64, 4) void gat_agg(
                        const int* __restrict__ rowptr, const int2* __restrict__ csr,
                        const u16* __restrict__ XL, const float* __restrict__ XR,
                        const u16* __restrict__ eah,  // [E][4] bf16
                        const float* __restrict__ We, const float* __restrict__ att,
                        const float* __restrict__ bias, float* __restrict__ out,
                        const void* __restrict__ batch, const int* __restrict__ flags,
                        float* __restrict__ pool, float* __restrict__ cnt) {
    const int Dout = H * 64;
    const int dst = blockIdx.x;
    const int t = threadIdx.x;
    const int h = t >> 6;            // wave == head
    const int lane = t & 63;
    const int g = lane >> 4;         // edge-group 0..3
    const int k = lane & 15;         // channel-slot
    const int c0 = h * 64 + k * 4;   // first of this lane's 4 channels

    const float4 w0 = *(const float4*)&We[0 * Dout + c0];
    const float4 w1 = *(const float4*)&We[1 * Dout + c0];
    const float4 w2 = *(const float4*)&We[2 * Dout + c0];
    const float4 w3 = *(const float4*)&We[3 * Dout + c0];
    const float4 at = *(const float4*)&att[c0];
    const float4 xr = *(const float4*)&XR[dst * Dout + c0];

    // pair views for packed math
    const f32x2 w0a = pk2(w0.x, w0.y), w0b = pk2(w0.z, w0.w);
    const f32x2 w1a = pk2(w1.x, w1.y), w1b = pk2(w1.z, w1.w);
    const f32x2 w2a = pk2(w2.x, w2.y), w2b = pk2(w2.z, w2.w);
    const f32x2 w3a = pk2(w3.x, w3.y), w3b = pk2(w3.z, w3.w);
    const f32x2 ata = pk2(at.x, at.y), atb = pk2(at.z, at.w);
    const f32x2 xra = pk2(xr.x, xr.y), xrb = pk2(xr.z, xr.w);
    const f32x2 leak = psplat(0.2f);

    const int i0 = rowptr[dst], i1 = rowptr[dst + 1];
    const int niter = (i1 - i0 + 3) >> 2;

    float l = 0.f;
    f32x2 acca = psplat(0.f), accb = psplat(0.f);

#define GAT_EDGE_BODY(E_IDX)                                                     \
    {                                                                            \
        int e_ = (E_IDX);                                                        \
        bool valid_ = e_ < i1;                                                   \
        int2 se_ = csr[valid_ ? e_ : i0];                                        \
        uint2 xu_ = *(const uint2*)&XL[se_.x * Dout + c0];                       \
        uint2 au_ = *(const uint2*)&eah[se_.y * 4];                              \
        f32x2 xla_ = pk2(lou(xu_.x), hiu(xu_.x));                                \
        f32x2 xlb_ = pk2(lou(xu_.y), hiu(xu_.y));                                \
        f32x2 A0_ = psplat(lou(au_.x));                                          \
        f32x2 A1_ = psplat(hiu(au_.x));                                          \
        f32x2 A2_ = psplat(lou(au_.y));                                          \
        f32x2 A3_ = psplat(hiu(au_.y));                                          \
        f32x2 za_ = pfma(A0_, w0a, pfma(A1_, w1a, pfma(A2_, w2a, pfma(A3_, w3a, xla_ + xra)))); \
        f32x2 zb_ = pfma(A0_, w0b, pfma(A1_, w1b, pfma(A2_, w2b, pfma(A3_, w3b, xlb_ + xrb)))); \
        za_ = pmax(za_, leak * za_);                                             \
        zb_ = pmax(zb_, leak * zb_);                                             \
        f32x2 tv_ = pfma(za_, ata, zb_ * atb);                                   \
        float v_ = tv_.x + tv_.y;                                                \
        v_ += __shfl_xor(v_, 1);                                                 \
        v_ += __shfl_xor(v_, 2);                                                 \
        v_ += __shfl_xor(v_, 4);                                                 \
        v_ += __shfl_xor(v_, 8);                                                 \
        float p_ = valid_ ? __expf(v_) : 0.f;                                    \
        l += p_;                                                                 \
        f32x2 ps_ = psplat(p_);                                                  \
        acca = pfma(ps_, xla_, acca);                                            \
        accb = pfma(ps_, xlb_, accb);                                            \
    }

    int it = 0;
    for (; it + 2 <= niter; it += 2) {
        int eb = i0 + g + it * 4;
        GAT_EDGE_BODY(eb)
        GAT_EDGE_BODY(eb + 4)
    }
    if (it < niter) {
        GAT_EDGE_BODY(i0 + g + it * 4)
    }
#undef GAT_EDGE_BODY

    // combine the 4 edge-groups (once per dst)
    l += __shfl_xor(l, 16);      l += __shfl_xor(l, 32);
    acca.x += __shfl_xor(acca.x, 16); acca.x += __shfl_xor(acca.x, 32);
    acca.y += __shfl_xor(acca.y, 16); acca.y += __shfl_xor(acca.y, 32);
    accb.x += __shfl_xor(accb.x, 16); accb.x += __shfl_xor(accb.x, 32);
    accb.y += __shfl_xor(accb.y, 16); accb.y += __shfl_xor(accb.y, 32);

    if (g == 0) {
        float inv = 1.f / (l + 1e-16f);
        const float4 b4 = *(const float4*)&bias[c0];
        float o0 = fmaf(acca.x, inv, b4.x);
        float o1 = fmaf(acca.y, inv, b4.y);
        float o2 = fmaf(accb.x, inv, b4.z);
        float o3 = fmaf(accb.y, inv, b4.w);
        if (ELU) {
            o0 = o0 > 0.f ? o0 : expf(o0) - 1.f;
            o1 = o1 > 0.f ? o1 : expf(o1) - 1.f;
            o2 = o2 > 0.f ? o2 : expf(o2) - 1.f;
            o3 = o3 > 0.f ? o3 : expf(o3) - 1.f;
        }
        if (POOLF) {
            int b = idx_at(batch, dst, flags[2]);
            atomicAdd(&pool[b * 64 + c0 + 0], o0);
            atomicAdd(&pool[b * 64 + c0 + 1], o1);
            atomicAdd(&pool[b * 64 + c0 + 2], o2);
            atomicAdd(&pool[b * 64 + c0 + 3], o3);
            if (lane == 0) atomicAdd(&cnt[b], 1.f);
        } else {
            *(float4*)&out[dst * Dout + c0] = make_float4(o0, o1, o2, o3);
        }
    }
}

// ---------------------------------------------------------------------------
// MLP head: one block (64 threads) per graph; fp32 output
// ---------------------------------------------------------------------------
__global__ void mlp_head(const float* __restrict__ pool, const float* __restrict__ cnt,
                         const float* __restrict__ mW1, const float* __restrict__ mb1,
                         const float* __restrict__ mW2, const float* __restrict__ mb2,
                         const float* __restrict__ mW3, const float* __restrict__ mb3,
                         float* __restrict__ out) {
    __shared__ float g[64], s1[32], s2[16];
    int b = blockIdx.x, t = threadIdx.x;
    float c = fmaxf(cnt[b], 1.f);
    g[t] = pool[b * 64 + t] / c;
    __syncthreads();
    if (t < 32) {
        float a = 0.f;
        for (int k = 0; k < 64; k++) a = fmaf(g[k], mW1[k * 32 + t], a);
        s1[t] = fmaxf(a + mb1[t], 0.f);
    }
    __syncthreads();
    if (t < 16) {
        float a = 0.f;
        for (int k = 0; k < 32; k++) a = fmaf(s1[k], mW2[k * 16 + t], a);
        s2[t] = fmaxf(a + mb2[t], 0.f);
    }
    __syncthreads();
    if (t < 4) {
        float a = 0.f;
        for (int k = 0; k < 16; k++) a = fmaf(s2[k], mW3[k * 4 + t], a);
        out[b * 4 + t] = a + mb3[t];
    }
}

// ---------------------------------------------------------------------------

extern "C" void kernel_launch(void* const* d_in, const int* in_sizes, int n_in,
                              void* d_out, int out_size, void* d_ws, size_t ws_size,
                              hipStream_t stream) {
    const void* ei    = d_in[1];
    const void* batch = d_in[3];

    // ---- canonicalization table: the 29 float inputs in dict order ----
    int fidx[29];
    fidx[0] = 0;  // x
    fidx[1] = 2;  // edge_attr
    for (int i = 0; i < 21; i++) fidx[2 + i] = 4 + i;
    for (int i = 0; i < 6; i++) fidx[23 + i] = 25 + i;

    Segs S;
    int off = 0;
    for (int i = 0; i < 29; i++) {
        S.src[i] = d_in[fidx[i]];
        S.off[i] = off;
        off += in_sizes[fidx[i]];
    }
    S.off[29] = off;
    const int total = off;

    // ---- workspace layout (16B-aligned sections) ----
    char* p = (char*)d_ws;
    int*   FLAGS  = (int*)p;                 p += 16;
    float* CONV   = (float*)p;               p += sizeof(float) * total;  p = align16(p);
    int*   DEG    = (int*)p;                 p += sizeof(int) * NNODES;
    int*   ROWPTR = (int*)p;                 p += sizeof(int) * (NNODES + 1);
    int*   CURSOR = (int*)p;                 p += sizeof(int) * (NNODES + 1);  p = align16(p);
    int2*  CSR    = (int2*)p;                p += sizeof(int2) * NEDGES;  p = align16(p);
    u16*   EAH    = (u16*)p;                 p += sizeof(u16) * NEDGES * 4;  p = align16(p);
    u16*   WT2L   = (u16*)p;                 p += sizeof(u16) * 256 * 256;
    u16*   WT2R   = (u16*)p;                 p += sizeof(u16) * 256 * 256;
    u16*   WT3L   = (u16*)p;                 p += sizeof(u16) * 64 * 256;
    u16*   WT3R   = (u16*)p;                 p += sizeof(u16) * 64 * 256;  p = align16(p);
    u16*   XLb    = (u16*)p;                 p += sizeof(u16) * NNODES * 256;  p = align16(p);
    float* XRb    = (float*)p;               p += sizeof(float) * NNODES * 256;
    float* ACC    = (float*)p;               p += sizeof(float) * NNODES * 256;
    float* POOL   = (float*)p;               p += sizeof(float) * NGRAPH * 64;
    float* CNT    = (float*)p;               p += sizeof(float) * NGRAPH;

    const float* CX  = CONV + S.off[0];
    const float* CP[21];
    for (int i = 0; i < 21; i++) CP[i] = CONV + S.off[2 + i];
    const float* CmW1 = CONV + S.off[23];
    const float* Cmb1 = CONV + S.off[24];
    const float* CmW2 = CONV + S.off[25];
    const float* Cmb2 = CONV + S.off[26];
    const float* CmW3 = CONV + S.off[27];
    const float* Cmb3 = CONV + S.off[28];

    // ---- sniff + fused preprocessing (convert/ea/W-pack/zero-init) ----
    sniff_all<<<1, 256, 0, stream>>>(d_in[0], ei, batch, FLAGS);
    int pre_total = total + NEDGES * 4 + 65536 * 2 + 16384 * 2 + NNODES + NGRAPH * 65;
    preprocess<<<(pre_total + 255) / 256, 256, 0, stream>>>(
        S, FLAGS, CONV, total, EAH, WT2L, WT2R, WT3L, WT3R, DEG, POOL);

    // ---- CSR build (graph identical across layers: build once) ----
    csr_hist<<<(NEDGES + 255) / 256, 256, 0, stream>>>(ei, FLAGS, DEG);
    csr_scan<<<1, 1024, 0, stream>>>(DEG, ROWPTR, CURSOR);
    csr_scatter<<<(NEDGES + 255) / 256, 256, 0, stream>>>(ei, FLAGS, CURSOR, CSR);

    // ---- layer 1: x (N x 12) -> ACC (N x 256), ELU ----
    lin_gemm<4, 12, 256, false><<<NNODES / 16, 256, 0, stream>>>(CX, CP[0], CP[1], CP[2], CP[3], XLb, XRb);
    gat_agg<4, true, false><<<NNODES, 256, 0, stream>>>(ROWPTR, CSR, XLb, XRb, EAH,
        CP[4], CP[5], CP[6], ACC, batch, FLAGS, POOL, CNT);

    // ---- layer 2: ACC (N x 256) -> ACC, ELU (MFMA GEMM) ----
    lin_gemm_mfma<256><<<NNODES / 16, 256, 0, stream>>>(ACC, WT2L, CP[8], WT2R, CP[10], XLb, XRb);
    gat_agg<4, true, false><<<NNODES, 256, 0, stream>>>(ROWPTR, CSR, XLb, XRb, EAH,
        CP[11], CP[12], CP[13], ACC, batch, FLAGS, POOL, CNT);

    // ---- layer 3: ACC (N x 256) -> pooled directly (MFMA GEMM + fused pool) ----
    lin_gemm_mfma<64><<<NNODES / 16, 256, 0, stream>>>(ACC, WT3L, CP[15], WT3R, CP[17], XLb, XRb);
    gat_agg<1, false, true><<<NNODES, 64, 0, stream>>>(ROWPTR, CSR, XLb, XRb, EAH,
        CP[18], CP[19], CP[20], ACC, batch, FLAGS, POOL, CNT);

    // ---- MLP head ----
    mlp_head<<<NGRAPH, 64, 0, stream>>>(POOL, CNT, CmW1, Cmb1, CmW2, Cmb2, CmW3, Cmb3, (float*)d_out);
}